// Round 6
// baseline (5742.977 us; speedup 1.0000x reference)
//
#include <hip/hip_runtime.h>
#include <math.h>

typedef _Float16 half8 __attribute__((ext_vector_type(8)));
typedef float float4v __attribute__((ext_vector_type(4)));

constexpr int Lc   = 2048;  // L_IN
constexpr int DECc = 64;    // DEC_LEN
constexpr int Hc   = 128;   // H
constexpr int EMBc = 16;    // EMB
constexpr int INc  = 18;    // IN_SIZE
constexpr int NBc  = 2;     // batches per block  (R6: 4->2, grid 256->512 => 2 blocks/CU)
constexpr int NTc  = 512;   // threads per block (8 waves)
constexpr int KT   = 5;     // k-tiles of 32 (z padded to 160)
constexpr int GS   = 520;   // g_lds per-batch stride (512 + 8 pad)

__device__ __forceinline__ float sigm(float x) {
    return 1.0f / (1.0f + exp2f(-1.44269504f * x));
}
__device__ __forceinline__ float tanh_(float x) {
    return 2.0f / (1.0f + exp2f(-2.88539008f * x)) - 1.0f;
}
__device__ __forceinline__ float softplus_(float x) {
    return 0.69314718f * log2f(1.0f + exp2f(1.44269504f * x));
}

// z LDS layout = B-fragment order for mfma_f32_16x16x32_f16 (verified R4/R5):
// frag kt: lane l holds halves [l*8..l*8+8) = B[k = kt*32 + (l>>4)*8 + j][n = l&15]
__device__ __forceinline__ int zslot(int k, int b) {
    return (k >> 5) * 512 + (b + 16 * ((k & 31) >> 3)) * 8 + (k & 7);
}

__global__ __launch_bounds__(NTc, 4) void rnnar_kernel(
    const int*   __restrict__ cat_in,  const float* __restrict__ cont_in,
    const float* __restrict__ X_in,    const int*   __restrict__ cat_out,
    const float* __restrict__ cont_out,const float* __restrict__ emb_table,
    const float* __restrict__ cont_w,
    const float* __restrict__ Wih_e, const float* __restrict__ Whh_e, const float* __restrict__ b_e,
    const float* __restrict__ Wih_d, const float* __restrict__ Whh_d, const float* __restrict__ b_d,
    const float* __restrict__ Wm, const float* __restrict__ bm,
    const float* __restrict__ Ws, const float* __restrict__ bs,
    const float* __restrict__ Wv, const float* __restrict__ bv,
    float* __restrict__ out)
{
    __shared__ _Float16      z_lds[KT * 512];       // 5 KB  (B-frags)
    __shared__ float         g_lds[NBc * GS];       // gate pre-activations (incl bias)
    __shared__ float         h32_lds[NBc * 132];    // fp32 h for decoder heads
    __shared__ unsigned char catb[NBc * 2048];      // cat_in indices (CARD=200<256)
    __shared__ unsigned char catob[NBc * DECc];

    const int tid  = threadIdx.x;
    const int lane = tid & 63;
    const int wv   = tid >> 6;        // wave 0..7
    const int quad = lane >> 4;       // 0..3
    const int col  = lane & 15;       // C-col (= batch)
    const int b0   = blockIdx.x * NBc;
    const float w00 = cont_w[0];

    // x-writer role (tid < INc*NBc = 36)
    const int xk = tid / NBc, xb = tid % NBc, xgb = b0 + xb;
    // phase-2 role: thread owns cell m of batch pb (tid < 128*NBc)
    const int m = tid & (Hc - 1), pb = tid >> 7;

    // zero z (padding + unused cols must stay 0 forever)
    {
        int* z32 = (int*)z_lds;
        for (int i = tid; i < KT * 256; i += NTc) z32[i] = 0;
    }
    // preload categorical indices into LDS (coalesced global reads)
    for (int i = tid; i < NBc * 2048; i += NTc) {
        const int b = i >> 11, t = i & 2047;
        catb[i] = (unsigned char)cat_in[(b0 + b) * Lc + t];
    }
    for (int i = tid; i < NBc * DECc; i += NTc) {
        const int b = i >> 6, t = i & 63;
        catob[i] = (unsigned char)cat_out[(b0 + b) * DECc + t];
    }

    // ---- A-fragments: wave wv owns row-tiles {wv + 8i} = gate i, cells 16wv..16wv+15 ----
    half8 Af[4][KT];
    float4v bias4[4];                      // acc init = bias (C rows quad*4+r, same all cols)
    const int cell_base = 16 * wv + quad * 4;

    #define LOAD_AB(WIH, WHH, BB)                                              \
    {                                                                          \
        _Pragma("unroll")                                                      \
        for (int i = 0; i < 4; ++i) {                                          \
            const int row = 128 * i + 16 * wv + col;                           \
            _Pragma("unroll")                                                  \
            for (int kt = 0; kt < KT; ++kt) {                                  \
                half8 f;                                                       \
                _Pragma("unroll")                                              \
                for (int j = 0; j < 8; ++j) {                                  \
                    const int k = 32 * kt + quad * 8 + j;                      \
                    float v = 0.0f;                                            \
                    if (k < INc)            v = WIH[row * INc + k];            \
                    else if (k < INc + Hc)  v = WHH[row * Hc + (k - INc)];     \
                    f[j] = (_Float16)v;                                        \
                }                                                              \
                Af[i][kt] = f;                                                 \
            }                                                                  \
            float4v bb;                                                        \
            _Pragma("unroll")                                                  \
            for (int r = 0; r < 4; ++r) bb[r] = BB[128 * i + cell_base + r];   \
            bias4[i] = bb;                                                     \
        }                                                                      \
    }

    LOAD_AB(Wih_e, Whh_e, b_e);

    __syncthreads();   // z zero + catb visible

    // x(0) stored; xreg = x(1) (2-step pipeline reg)
    float xreg = 0.f;
    if (tid < INc * NBc) {
        float v0, v1;
        if (xk < EMBc) {
            v0 = emb_table[(int)catb[xb * 2048 + 0] * EMBc + xk];
            v1 = emb_table[(int)catb[xb * 2048 + 1] * EMBc + xk];
        } else if (xk == EMBc) {
            v0 = cont_in[xgb * Lc + 0] * w00;
            v1 = cont_in[xgb * Lc + 1] * w00;
        } else {
            v0 = X_in[xgb * Lc + 0];
            v1 = X_in[xgb * Lc + 1];
        }
        z_lds[zslot(xk, xb)] = (_Float16)v0;
        xreg = v1;
    }
    __syncthreads();

    float c_reg = 0.f;
    const _Float16* zp = z_lds + lane * 8;

    // ===================== encoder =====================
    for (int t = 0; t < Lc; ++t) {
        // issue x(t+2) loads (2-step window covers latency)
        float xf = 0.f;
        if (tid < INc * NBc) {
            const int t2 = (t + 2 < Lc) ? t + 2 : Lc - 1;
            if (xk < EMBc)       xf = emb_table[(int)catb[xb * 2048 + t2] * EMBc + xk];
            else if (xk == EMBc) xf = cont_in[xgb * Lc + t2] * w00;
            else                 xf = X_in[xgb * Lc + t2];
        }

        // phase 1: MFMA gates
        half8 bf[KT];
        #pragma unroll
        for (int kt = 0; kt < KT; ++kt) bf[kt] = *(const half8*)(zp + kt * 512);
        float4v acc[4];
        #pragma unroll
        for (int i = 0; i < 4; ++i) {
            float4v a = bias4[i];
            #pragma unroll
            for (int kt = 0; kt < KT; ++kt)
                a = __builtin_amdgcn_mfma_f32_16x16x32_f16(Af[i][kt], bf[kt], a, 0, 0, 0);
            acc[i] = a;
        }
        if (col < NBc) {
            #pragma unroll
            for (int i = 0; i < 4; ++i)
                *(float4v*)(g_lds + col * GS + i * 128 + cell_base) = acc[i];
        }
        __syncthreads();

        // phase 2: one cell-update per thread (cell m, batch pb)
        if (tid < Hc * NBc) {
            const float gi = g_lds[pb * GS + m];
            const float gf = g_lds[pb * GS + 128 + m];
            const float gg = g_lds[pb * GS + 256 + m];
            const float go = g_lds[pb * GS + 384 + m];
            const float cn = sigm(gf) * c_reg + sigm(gi) * tanh_(gg);
            c_reg = cn;
            z_lds[zslot(INc + m, pb)] = (_Float16)(sigm(go) * tanh_(cn));
        }
        if (tid < INc * NBc) z_lds[zslot(xk, xb)] = (_Float16)xreg;  // x(t+1)
        xreg = xf;
        __syncthreads();
    }

    // ===================== decoder =====================
    LOAD_AB(Wih_d, Whh_d, b_d);

    if (tid < INc * NBc) {
        float v;
        if (xk < EMBc)       v = emb_table[(int)catb[xb * 2048 + (Lc - 1)] * EMBc + xk];
        else if (xk == EMBc) v = cont_in[xgb * Lc + Lc - 1] * w00;
        else                 v = X_in[xgb * Lc + Lc - 1];
        z_lds[zslot(xk, xb)] = (_Float16)v;
    }
    __syncthreads();

    const float bm0 = bm[0], bs0 = bs[0];

    for (int t = 0; t < DECc; ++t) {
        // prefetch feats_out[:, t] -> x(t+1) (k<17; k=17 slot is mu, written by heads)
        float xf = 0.f;
        if (tid < INc * NBc && xk < INc - 1) {
            if (xk < EMBc) xf = emb_table[(int)catob[xb * DECc + t] * EMBc + xk];
            else           xf = cont_out[xgb * DECc + t] * w00;
        }

        half8 bf[KT];
        #pragma unroll
        for (int kt = 0; kt < KT; ++kt) bf[kt] = *(const half8*)(zp + kt * 512);
        float4v acc[4];
        #pragma unroll
        for (int i = 0; i < 4; ++i) {
            float4v a = bias4[i];
            #pragma unroll
            for (int kt = 0; kt < KT; ++kt)
                a = __builtin_amdgcn_mfma_f32_16x16x32_f16(Af[i][kt], bf[kt], a, 0, 0, 0);
            acc[i] = a;
        }
        if (col < NBc) {
            #pragma unroll
            for (int i = 0; i < 4; ++i)
                *(float4v*)(g_lds + col * GS + i * 128 + cell_base) = acc[i];
        }
        __syncthreads();

        // phase 2
        if (tid < Hc * NBc) {
            const float gi = g_lds[pb * GS + m];
            const float gf = g_lds[pb * GS + 128 + m];
            const float gg = g_lds[pb * GS + 256 + m];
            const float go = g_lds[pb * GS + 384 + m];
            const float cn = sigm(gf) * c_reg + sigm(gi) * tanh_(gg);
            c_reg = cn;
            const float hv = sigm(go) * tanh_(cn);
            z_lds[zslot(INc + m, pb)] = (_Float16)hv;
            h32_lds[pb * 132 + m] = hv;
        }
        if (tid < INc * NBc && xk < INc - 1) z_lds[zslot(xk, xb)] = (_Float16)xf;
        __syncthreads();

        // phase 3: heads (mu, std, v[0..3]) per batch
        if (tid < NBc * 8) {
            const int b = tid >> 3, o = tid & 7;
            if (o < 6) {
                const float* wvp = (o == 0) ? Wm : (o == 1) ? Ws : (Wv + (o - 2) * Hc);
                float s = 0.0f;
                #pragma unroll 8
                for (int k = 0; k < Hc; ++k) s += wvp[k] * h32_lds[b * 132 + k];
                const int gb = b0 + b;
                if (o == 0) {
                    const float mu = s + bm0;
                    out[gb * DECc + t] = mu;
                    z_lds[zslot(INc - 1, b)] = (_Float16)mu;   // mu feedback
                } else if (o == 1) {
                    out[65536 + gb * DECc + t] = softplus_(s + bs0);
                } else {
                    out[131072 + (gb * DECc + t) * 4 + (o - 2)] = s + bv[o - 2];
                }
            }
        }
        __syncthreads();
    }
    #undef LOAD_AB
}

extern "C" void kernel_launch(void* const* d_in, const int* in_sizes, int n_in,
                              void* d_out, int out_size, void* d_ws, size_t ws_size,
                              hipStream_t stream) {
    rnnar_kernel<<<1024 / NBc, NTc, 0, stream>>>(
        (const int*)d_in[0],   (const float*)d_in[1],  (const float*)d_in[2],
        (const int*)d_in[3],   (const float*)d_in[4],  (const float*)d_in[5],
        (const float*)d_in[6],
        (const float*)d_in[7], (const float*)d_in[8],  (const float*)d_in[9],
        (const float*)d_in[10],(const float*)d_in[11], (const float*)d_in[12],
        (const float*)d_in[13],(const float*)d_in[14],
        (const float*)d_in[15],(const float*)d_in[16],
        (const float*)d_in[17],(const float*)d_in[18],
        (float*)d_out);
}

// Round 7
// 2263.135 us; speedup vs baseline: 2.5376x; 2.5376x over previous
//
#include <hip/hip_runtime.h>
#include <math.h>

typedef _Float16 half8 __attribute__((ext_vector_type(8)));
typedef float float4v __attribute__((ext_vector_type(4)));

constexpr int Lc   = 2048;  // L_IN
constexpr int DECc = 64;    // DEC_LEN
constexpr int Hc   = 128;   // H
constexpr int EMBc = 16;    // EMB
constexpr int INc  = 18;    // IN_SIZE
constexpr int NBc  = 4;     // batches per block
constexpr int NTc  = 1024;  // threads per block (16 waves -> 4 waves/SIMD)
constexpr int KT   = 5;     // k-tiles of 32 (z padded to 160)
constexpr int GS   = 520;   // g_lds per-batch stride (512 + 8 pad)

__device__ __forceinline__ float sigm(float x) {
    return 1.0f / (1.0f + exp2f(-1.44269504f * x));
}
__device__ __forceinline__ float tanh_(float x) {
    return 2.0f / (1.0f + exp2f(-2.88539008f * x)) - 1.0f;
}
__device__ __forceinline__ float softplus_(float x) {
    return 0.69314718f * log2f(1.0f + exp2f(1.44269504f * x));
}

// z LDS layout = B-fragment order for mfma_f32_16x16x32_f16 (verified R4/R5):
// frag kt: lane l holds halves [l*8..l*8+8) = B[k = kt*32 + (l>>4)*8 + j][n = l&15]
__device__ __forceinline__ int zslot(int k, int b) {
    return (k >> 5) * 512 + (b + 16 * ((k & 31) >> 3)) * 8 + (k & 7);
}

__global__ __launch_bounds__(NTc, 1) void rnnar_kernel(
    const int*   __restrict__ cat_in,  const float* __restrict__ cont_in,
    const float* __restrict__ X_in,    const int*   __restrict__ cat_out,
    const float* __restrict__ cont_out,const float* __restrict__ emb_table,
    const float* __restrict__ cont_w,
    const float* __restrict__ Wih_e, const float* __restrict__ Whh_e, const float* __restrict__ b_e,
    const float* __restrict__ Wih_d, const float* __restrict__ Whh_d, const float* __restrict__ b_d,
    const float* __restrict__ Wm, const float* __restrict__ bm,
    const float* __restrict__ Ws, const float* __restrict__ bs,
    const float* __restrict__ Wv, const float* __restrict__ bv,
    float* __restrict__ out)
{
    __shared__ _Float16      z_lds[KT * 512];       // 5 KB  (B-frags)
    __shared__ float         g_lds[NBc * GS];       // 8.3 KB gate pre-activations (incl bias)
    __shared__ float         h32_lds[NBc * 132];    // 2.1 KB fp32 h for decoder heads
    __shared__ unsigned char catb[NBc * 2048];      // 8 KB  cat_in indices (CARD=200<256)
    __shared__ unsigned char catob[NBc * DECc];     // 256 B

    const int tid  = threadIdx.x;
    const int lane = tid & 63;
    const int wv   = tid >> 6;        // wave 0..15
    const int quad = lane >> 4;       // 0..3
    const int col  = lane & 15;       // C-col (= batch)
    const int b0   = blockIdx.x * NBc;
    const float w00 = cont_w[0];

    // x-writer role: waves 8-9 (xw in [0,72))
    const int xw = tid - 512;
    const int xk = xw >> 2, xb = xw & 3, xgb = b0 + xb;
    const bool is_xw = (xw >= 0) && (xw < INc * NBc);
    // phase-2 role: waves 0-7, thread owns cell m of batch pb
    const int m = tid & (Hc - 1), pb = tid >> 7;    // valid when tid < 512

    // zero z (padding + unused cols must stay 0 forever)
    {
        int* z32 = (int*)z_lds;
        for (int i = tid; i < KT * 256; i += NTc) z32[i] = 0;
    }
    // preload categorical indices into LDS (coalesced global reads)
    for (int i = tid; i < NBc * 2048; i += NTc) {
        const int b = i >> 11, t = i & 2047;
        catb[i] = (unsigned char)cat_in[(b0 + b) * Lc + t];
    }
    if (tid < NBc * DECc) {
        const int b = tid >> 6, t = tid & 63;
        catob[tid] = (unsigned char)cat_out[(b0 + b) * DECc + t];
    }

    // ---- A-fragments: wave wv owns row-tiles {2wv, 2wv+1} = rows 32wv..32wv+31 ----
    half8 Af[2][KT];
    float4v bias4[2];                 // acc init = bias (C rows quad*4+r, same all cols)

    #define LOAD_AB(WIH, WHH, BB)                                              \
    {                                                                          \
        _Pragma("unroll")                                                      \
        for (int i = 0; i < 2; ++i) {                                          \
            const int row = (2 * wv + i) * 16 + col;                           \
            _Pragma("unroll")                                                  \
            for (int kt = 0; kt < KT; ++kt) {                                  \
                half8 f;                                                       \
                _Pragma("unroll")                                              \
                for (int j = 0; j < 8; ++j) {                                  \
                    const int k = 32 * kt + quad * 8 + j;                      \
                    float v = 0.0f;                                            \
                    if (k < INc)            v = WIH[row * INc + k];            \
                    else if (k < INc + Hc)  v = WHH[row * Hc + (k - INc)];     \
                    f[j] = (_Float16)v;                                        \
                }                                                              \
                Af[i][kt] = f;                                                 \
            }                                                                  \
            float4v bb;                                                        \
            _Pragma("unroll")                                                  \
            for (int r = 0; r < 4; ++r)                                        \
                bb[r] = BB[(2 * wv + i) * 16 + quad * 4 + r];                  \
            bias4[i] = bb;                                                     \
        }                                                                      \
    }

    LOAD_AB(Wih_e, Whh_e, b_e);

    __syncthreads();   // z zero + catb visible

    // x(0) stored; xreg = x(1) (2-step pipeline reg)
    float xreg = 0.f;
    if (is_xw) {
        float v0, v1;
        if (xk < EMBc) {
            v0 = emb_table[(int)catb[xb * 2048 + 0] * EMBc + xk];
            v1 = emb_table[(int)catb[xb * 2048 + 1] * EMBc + xk];
        } else if (xk == EMBc) {
            v0 = cont_in[xgb * Lc + 0] * w00;
            v1 = cont_in[xgb * Lc + 1] * w00;
        } else {
            v0 = X_in[xgb * Lc + 0];
            v1 = X_in[xgb * Lc + 1];
        }
        z_lds[zslot(xk, xb)] = (_Float16)v0;
        xreg = v1;
    }
    __syncthreads();

    float c_reg = 0.f;
    const _Float16* zp = z_lds + lane * 8;

    // ===================== encoder =====================
    for (int t = 0; t < Lc; ++t) {
        // waves 8-9: issue x(t+2) loads (2-step window covers latency)
        float xf = 0.f;
        if (is_xw) {
            const int t2 = (t + 2 < Lc) ? t + 2 : Lc - 1;
            if (xk < EMBc)       xf = emb_table[(int)catb[xb * 2048 + t2] * EMBc + xk];
            else if (xk == EMBc) xf = cont_in[xgb * Lc + t2] * w00;
            else                 xf = X_in[xgb * Lc + t2];
        }

        // phase 1: MFMA gates (2 row-tiles per wave)
        half8 bf[KT];
        #pragma unroll
        for (int kt = 0; kt < KT; ++kt) bf[kt] = *(const half8*)(zp + kt * 512);
        #pragma unroll
        for (int i = 0; i < 2; ++i) {
            float4v a = bias4[i];
            #pragma unroll
            for (int kt = 0; kt < KT; ++kt)
                a = __builtin_amdgcn_mfma_f32_16x16x32_f16(Af[i][kt], bf[kt], a, 0, 0, 0);
            if (col < NBc)
                *(float4v*)(g_lds + col * GS + (2 * wv + i) * 16 + quad * 4) = a;
        }
        __syncthreads();

        // phase 2 (waves 0-7): one cell-update per thread (cell m, batch pb)
        if (tid < Hc * NBc) {
            const float gi = g_lds[pb * GS + m];
            const float gf = g_lds[pb * GS + 128 + m];
            const float gg = g_lds[pb * GS + 256 + m];
            const float go = g_lds[pb * GS + 384 + m];
            const float cn = sigm(gf) * c_reg + sigm(gi) * tanh_(gg);
            c_reg = cn;
            z_lds[zslot(INc + m, pb)] = (_Float16)(sigm(go) * tanh_(cn));
        }
        if (is_xw) z_lds[zslot(xk, xb)] = (_Float16)xreg;  // x(t+1)
        xreg = xf;
        __syncthreads();
    }

    // ===================== decoder =====================
    LOAD_AB(Wih_d, Whh_d, b_d);

    if (is_xw) {
        float v;
        if (xk < EMBc)       v = emb_table[(int)catb[xb * 2048 + (Lc - 1)] * EMBc + xk];
        else if (xk == EMBc) v = cont_in[xgb * Lc + Lc - 1] * w00;
        else                 v = X_in[xgb * Lc + Lc - 1];
        z_lds[zslot(xk, xb)] = (_Float16)v;
    }
    __syncthreads();

    const float bm0 = bm[0], bs0 = bs[0];

    for (int t = 0; t < DECc; ++t) {
        // prefetch feats_out[:, t] -> x(t+1) (k<17; k=17 slot is mu, written by heads)
        float xf = 0.f;
        if (is_xw && xk < INc - 1) {
            if (xk < EMBc) xf = emb_table[(int)catob[xb * DECc + t] * EMBc + xk];
            else           xf = cont_out[xgb * DECc + t] * w00;
        }

        half8 bf[KT];
        #pragma unroll
        for (int kt = 0; kt < KT; ++kt) bf[kt] = *(const half8*)(zp + kt * 512);
        #pragma unroll
        for (int i = 0; i < 2; ++i) {
            float4v a = bias4[i];
            #pragma unroll
            for (int kt = 0; kt < KT; ++kt)
                a = __builtin_amdgcn_mfma_f32_16x16x32_f16(Af[i][kt], bf[kt], a, 0, 0, 0);
            if (col < NBc)
                *(float4v*)(g_lds + col * GS + (2 * wv + i) * 16 + quad * 4) = a;
        }
        __syncthreads();

        // phase 2 (waves 0-7)
        if (tid < Hc * NBc) {
            const float gi = g_lds[pb * GS + m];
            const float gf = g_lds[pb * GS + 128 + m];
            const float gg = g_lds[pb * GS + 256 + m];
            const float go = g_lds[pb * GS + 384 + m];
            const float cn = sigm(gf) * c_reg + sigm(gi) * tanh_(gg);
            c_reg = cn;
            const float hv = sigm(go) * tanh_(cn);
            z_lds[zslot(INc + m, pb)] = (_Float16)hv;
            h32_lds[pb * 132 + m] = hv;
        }
        if (is_xw && xk < INc - 1) z_lds[zslot(xk, xb)] = (_Float16)xf;
        __syncthreads();

        // phase 3: heads (mu, std, v[0..3]) per batch — wave 8
        if (xw >= 0 && xw < NBc * 8) {
            const int b = xw >> 3, o = xw & 7;
            if (o < 6) {
                const float* wvp = (o == 0) ? Wm : (o == 1) ? Ws : (Wv + (o - 2) * Hc);
                float s = 0.0f;
                #pragma unroll 8
                for (int k = 0; k < Hc; ++k) s += wvp[k] * h32_lds[b * 132 + k];
                const int gb = b0 + b;
                if (o == 0) {
                    const float mu = s + bm0;
                    out[gb * DECc + t] = mu;
                    z_lds[zslot(INc - 1, b)] = (_Float16)mu;   // mu feedback
                } else if (o == 1) {
                    out[65536 + gb * DECc + t] = softplus_(s + bs0);
                } else {
                    out[131072 + (gb * DECc + t) * 4 + (o - 2)] = s + bv[o - 2];
                }
            }
        }
        __syncthreads();
    }
    #undef LOAD_AB
}

extern "C" void kernel_launch(void* const* d_in, const int* in_sizes, int n_in,
                              void* d_out, int out_size, void* d_ws, size_t ws_size,
                              hipStream_t stream) {
    rnnar_kernel<<<1024 / NBc, NTc, 0, stream>>>(
        (const int*)d_in[0],   (const float*)d_in[1],  (const float*)d_in[2],
        (const int*)d_in[3],   (const float*)d_in[4],  (const float*)d_in[5],
        (const float*)d_in[6],
        (const float*)d_in[7], (const float*)d_in[8],  (const float*)d_in[9],
        (const float*)d_in[10],(const float*)d_in[11], (const float*)d_in[12],
        (const float*)d_in[13],(const float*)d_in[14],
        (const float*)d_in[15],(const float*)d_in[16],
        (const float*)d_in[17],(const float*)d_in[18],
        (float*)d_out);
}